// Round 12
// baseline (403.926 us; speedup 1.0000x reference)
//
#include <hip/hip_runtime.h>

typedef __attribute__((ext_vector_type(4))) int  i8x16;   // 16 packed int8 (4 VGPR MFMA operand)
typedef __attribute__((ext_vector_type(4))) int  i32x4;   // 16x16 i32 accumulator
typedef __attribute__((ext_vector_type(8))) short bf16x8;
typedef __attribute__((ext_vector_type(8))) unsigned short ushort8;
typedef __attribute__((ext_vector_type(4))) float f32x4;

__device__ __forceinline__ unsigned short f32_to_bf16(float f) {
    union { float f; unsigned int u; } v;
    v.f = f;
    unsigned int r = v.u + (0x7fffu + ((v.u >> 16) & 1u));
    return (unsigned short)(r >> 16);
}

__device__ __forceinline__ void gload_lds16(const void* g, void* l) {
    __builtin_amdgcn_global_load_lds(
        (const __attribute__((address_space(1))) unsigned int*)g,
        (__attribute__((address_space(3))) unsigned int*)l, 16, 0, 0);
}

// ---------------- x -> int8 per-row symmetric quantization ----------------
__global__ __launch_bounds__(256) void quantx_kernel(const float* __restrict__ x,
                                                     char* __restrict__ xq,
                                                     float* __restrict__ rs, int K) {
    const int row = blockIdx.x;
    const float4* xr = (const float4*)(x + (size_t)row * K);
    const int K4 = K >> 2;
    const int t = threadIdx.x;
    float am = 0.f;
    for (int i = t; i < K4; i += 256) {
        float4 v = xr[i];
        am = fmaxf(am, fmaxf(fmaxf(fabsf(v.x), fabsf(v.y)),
                             fmaxf(fabsf(v.z), fabsf(v.w))));
    }
    for (int off = 32; off; off >>= 1) am = fmaxf(am, __shfl_xor(am, off));
    __shared__ float ws[4];
    if ((t & 63) == 0) ws[t >> 6] = am;
    __syncthreads();
    am = fmaxf(fmaxf(ws[0], ws[1]), fmaxf(ws[2], ws[3]));
    const float inv = am > 0.f ? 127.f / am : 0.f;
    if (t == 0) rs[row] = am > 0.f ? am / 127.f : 0.f;
    int* dst = (int*)(xq + (size_t)row * K);
    for (int i = t; i < K4; i += 256) {
        float4 v = xr[i];
        int a = (int)rintf(v.x * inv), b = (int)rintf(v.y * inv);
        int c = (int)rintf(v.z * inv), d = (int)rintf(v.w * inv);
        dst[i] = (a & 255) | ((b & 255) << 8) | ((c & 255) << 16) | (d << 24);
    }
}

// ---------------- qweight int32 -> int8 ----------------
__global__ void convq_kernel(const int* __restrict__ q, char* __restrict__ qb, long n16) {
    long i = (long)blockIdx.x * blockDim.x + threadIdx.x;
    const long stride = (long)gridDim.x * blockDim.x;
    for (; i < n16; i += stride) {
        const int4* p = (const int4*)(q + i * 16);
        int4 a = p[0], b = p[1], c = p[2], d = p[3];
        int4 r;
        r.x = (a.x & 255) | ((a.y & 255) << 8) | ((a.z & 255) << 16) | (a.w << 24);
        r.y = (b.x & 255) | ((b.y & 255) << 8) | ((b.z & 255) << 16) | (b.w << 24);
        r.z = (c.x & 255) | ((c.y & 255) << 8) | ((c.z & 255) << 16) | (c.w << 24);
        r.w = (d.x & 255) | ((d.y & 255) << 8) | ((d.z & 255) << 16) | (d.w << 24);
        ((int4*)qb)[i] = r;
    }
}

// ---------------- 256x128 i8 GEMM, 2 blocks/CU (cross-block overlap) --------
// C[m,n] = sum_k xq[m,k]*qb[n,k] (i32); out = C * rs[m]*scale[n] + bias[n]
// 512 thr = 8 waves (4 wr x 2 wc), per-wave 64x64, BK=64 bytes, NT=K/64.
// mfma_i32_16x16x64_i8: lane l -> row l&15, k-bytes 16*(l>>4). acc 4x4xi32x4
// = 64 VGPR; total ~120 <= 128 (launch_bounds(512,4)) -> 16 waves/CU =
// 2 independent blocks -> cross-block MFMA/LDS overlap (m114), which the
// single-block barrier-locked schedules could never achieve (R2-R11 all 40-46%).
// LDS 48KB: A dbuf 2x16KB @0/16384 (256 rows x 64B), B dbuf 2x8KB @32768/40960.
// Swizzle (64B rows, 4 slots): logical slot s of row r at physical s^(r&3).
// Staging: thread c -> LDS c*16; source (c>>2)*K + ((c&3)^((c>>2)&3))*16.
// Fragment read: (stripe + l15)*64 + ((l4^(l15&3))<<4) + mf*1024 -> each
// wave-b128 covers a 1KB region exactly once = conflict-free.
__global__ __launch_bounds__(512, 4) void qgemm_i8_kernel(
    const char* __restrict__ A, const char* __restrict__ B,
    const float* __restrict__ rs, const float* __restrict__ scale,
    const float* __restrict__ bias, float* __restrict__ C, int M, int N, int K) {
    extern __shared__ char sm[];

    const int tid  = threadIdx.x;
    const int lane = tid & 63;
    const int w    = tid >> 6;
    const int wr   = w >> 1;                  // 0..3
    const int wc   = w & 1;                   // 0..1
    const int l15  = lane & 15;
    const int l4   = lane >> 4;

    // T1: bijective XCD swizzle (gridDim.x % 8 == 0 by construction)
    const int nwg = gridDim.x;
    const int bid = blockIdx.x;
    const int swz = (bid & 7) * (nwg >> 3) + (bid >> 3);
    const int nbn = N >> 7;
    const int m0  = (swz / nbn) << 8;
    const int n0  = (swz % nbn) << 7;

    // staging source offset (bytes): row = tid>>2, pslot = tid&3
    const size_t srcO = (size_t)(tid >> 2) * K +
                        (size_t)(((tid & 3) ^ ((tid >> 2) & 3)) << 4);
    const int ldsO = w << 10;                 // wave-uniform; lane*16 implicit

    const char* pA = A + (size_t)m0 * K;
    const char* pB = B + (size_t)n0 * K;
    const size_t hK = (size_t)128 * K;        // A staging round 1 (+128 rows)
    const int NT = K >> 6;

#define STAGE(Ab, Bb, kt) do {                                   \
        gload_lds16(pA + srcO + (size_t)(kt) * 64, (Ab) + ldsO); \
        gload_lds16(pA + srcO + hK + (size_t)(kt) * 64, (Ab) + ldsO + 8192); \
        gload_lds16(pB + srcO + (size_t)(kt) * 64, (Bb) + ldsO); } while (0)

    // fragment read bases (bytes)
    const int slot  = (l4 ^ (l15 & 3)) << 4;
    const int aBase = (wr * 64 + l15) * 64 + slot;   // + mf*1024
    const int bBase = (wc * 64 + l15) * 64 + slot;   // + nf*1024

    i32x4 acc[4][4];
#pragma unroll
    for (int mf = 0; mf < 4; ++mf)
#pragma unroll
        for (int nf = 0; nf < 4; ++nf) acc[mf][nf] = (i32x4){0, 0, 0, 0};

    // ---- prologue: stage tile0 + tile1 (6 gloads); 3 stay in flight ----
    STAGE(sm + 0, sm + 32768, 0);
    if (NT > 1) {
        STAGE(sm + 16384, sm + 40960, 1);
        asm volatile("s_waitcnt vmcnt(3)" ::: "memory");   // tile0 landed
    } else {
        asm volatile("s_waitcnt vmcnt(0)" ::: "memory");
    }
    __builtin_amdgcn_s_barrier();

    for (int t = 0; t < NT; ++t) {
        char* Ab = sm + (t & 1) * 16384;
        char* Bb = sm + 32768 + (t & 1) * 8192;

        i8x16 aF[4], bF[4];
#pragma unroll
        for (int mf = 0; mf < 4; ++mf)
            aF[mf] = *(const i8x16*)(Ab + aBase + mf * 1024);
#pragma unroll
        for (int nf = 0; nf < 4; ++nf)
            bF[nf] = *(const i8x16*)(Bb + bBase + nf * 1024);
        asm volatile("s_waitcnt lgkmcnt(0)" ::: "memory");
        __builtin_amdgcn_sched_barrier(0);
        __builtin_amdgcn_s_setprio(1);
#pragma unroll
        for (int mf = 0; mf < 4; ++mf)
#pragma unroll
            for (int nf = 0; nf < 4; ++nf)
                acc[mf][nf] = __builtin_amdgcn_mfma_i32_16x16x64_i8(
                    aF[mf], bF[nf], acc[mf][nf], 0, 0, 0);
        __builtin_amdgcn_s_setprio(0);

        if (t + 1 < NT) {
            __builtin_amdgcn_s_barrier();   // B1: all waves done reading cur
            if (t + 2 < NT) {
                STAGE(Ab, Bb, t + 2);       // re-stage cur with tile t+2
                asm volatile("s_waitcnt vmcnt(3)" ::: "memory");  // t+1 landed
            } else {
                asm volatile("s_waitcnt vmcnt(0)" ::: "memory");
            }
            __builtin_amdgcn_s_barrier();   // B2: publish tile t+1
        }
    }

    // ---- epilogue: out = acc * (rs[row]*scale[col]) + bias[col] ----
    // C/D 16x16 layout: col = l15, row = l4*4 + j
#pragma unroll
    for (int mf = 0; mf < 4; ++mf) {
        const int row0 = m0 + wr * 64 + mf * 16 + l4 * 4;
        float rsv[4];
#pragma unroll
        for (int j = 0; j < 4; ++j) rsv[j] = rs[row0 + j];
#pragma unroll
        for (int nf = 0; nf < 4; ++nf) {
            const int col = n0 + wc * 64 + nf * 16 + l15;
            const float sc = scale[col];
            const float bs = bias[col];
#pragma unroll
            for (int j = 0; j < 4; ++j)
                C[(size_t)(row0 + j) * N + col] =
                    (float)acc[mf][nf][j] * (rsv[j] * sc) + bs;
        }
    }
#undef STAGE
}

// ---------------- fallback (shape mismatch): 2-phase bf16, on-the-fly ----
__global__ __launch_bounds__(256) void qgemm_fb_kernel(
    const float* __restrict__ Af, const int* __restrict__ Bi,
    const float* __restrict__ scale, const float* __restrict__ bias,
    float* __restrict__ C, int M, int N, int K) {
    constexpr int BK = 64;
    __shared__ unsigned short lA[128 * BK];
    __shared__ unsigned short lB[128 * BK];
    const int t = threadIdx.x, lane = t & 63, w = t >> 6;
    const int wr = w >> 1, wc = w & 1;
    const int m0 = blockIdx.y * 128, n0 = blockIdx.x * 128;
    const int l15 = lane & 15, l4 = lane >> 4;
    f32x4 acc[4][4];
#pragma unroll
    for (int m = 0; m < 4; ++m)
#pragma unroll
        for (int n = 0; n < 4; ++n) acc[m][n] = (f32x4){0.f, 0.f, 0.f, 0.f};
    for (int k0 = 0; k0 < K; k0 += BK) {
        __syncthreads();
#pragma unroll
        for (int i = 0; i < 4; ++i) {
            const int off = i * 4096 + w * 1024 + lane * 16;
            const int row = off >> 7;
            const int col = (off & 127) >> 1;
            const float* pa = Af + (size_t)(m0 + row) * K + k0 + col;
            float4 a0 = *(const float4*)pa;
            float4 a1 = *(const float4*)(pa + 4);
            ushort8 va;
            va[0] = f32_to_bf16(a0.x); va[1] = f32_to_bf16(a0.y);
            va[2] = f32_to_bf16(a0.z); va[3] = f32_to_bf16(a0.w);
            va[4] = f32_to_bf16(a1.x); va[5] = f32_to_bf16(a1.y);
            va[6] = f32_to_bf16(a1.z); va[7] = f32_to_bf16(a1.w);
            *(ushort8*)((char*)lA + off) = va;
            const int* pb = Bi + (size_t)(n0 + row) * K + k0 + col;
            int4 b0 = *(const int4*)pb;
            int4 b1 = *(const int4*)(pb + 4);
            ushort8 vb;
            vb[0] = f32_to_bf16((float)b0.x); vb[1] = f32_to_bf16((float)b0.y);
            vb[2] = f32_to_bf16((float)b0.z); vb[3] = f32_to_bf16((float)b0.w);
            vb[4] = f32_to_bf16((float)b1.x); vb[5] = f32_to_bf16((float)b1.y);
            vb[6] = f32_to_bf16((float)b1.z); vb[7] = f32_to_bf16((float)b1.w);
            *(ushort8*)((char*)lB + off) = vb;
        }
        __syncthreads();
#pragma unroll
        for (int kk = 0; kk < BK; kk += 32) {
            bf16x8 af[4], bfr[4];
#pragma unroll
            for (int m = 0; m < 4; ++m)
                af[m] = *(const bf16x8*)&lA[(wr * 64 + m * 16 + l15) * BK + kk + l4 * 8];
#pragma unroll
            for (int n = 0; n < 4; ++n)
                bfr[n] = *(const bf16x8*)&lB[(wc * 64 + n * 16 + l15) * BK + kk + l4 * 8];
#pragma unroll
            for (int m = 0; m < 4; ++m)
#pragma unroll
                for (int n = 0; n < 4; ++n)
                    acc[m][n] = __builtin_amdgcn_mfma_f32_16x16x32_bf16(
                        af[m], bfr[n], acc[m][n], 0, 0, 0);
        }
    }
#pragma unroll
    for (int n = 0; n < 4; ++n) {
        const int col = n0 + wc * 64 + n * 16 + l15;
        const float sc = scale[col], bs = bias[col];
#pragma unroll
        for (int m = 0; m < 4; ++m) {
            const int row0 = m0 + wr * 64 + m * 16 + l4 * 4;
#pragma unroll
            for (int j = 0; j < 4; ++j)
                C[(size_t)(row0 + j) * N + col] = fmaf(acc[m][n][j], sc, bs);
        }
    }
}

extern "C" void kernel_launch(void* const* d_in, const int* in_sizes, int n_in,
                              void* d_out, int out_size, void* d_ws, size_t ws_size,
                              hipStream_t stream) {
    const float* x     = (const float*)d_in[0];
    const int*   q     = (const int*)d_in[1];
    const float* scale = (const float*)d_in[2];
    const float* bias  = (const float*)d_in[3];
    float*       out   = (float*)d_out;

    const int K = in_sizes[2];
    const int N = in_sizes[1] / K;
    const int M = in_sizes[0] / K;

    const size_t xq_b = (size_t)M * K;
    const size_t qb_b = (size_t)N * K;
    const size_t need = xq_b + qb_b + (size_t)M * 4;
    const int nwg = (M / 256) * (N / 128);

    if (ws_size >= need && (M % 256) == 0 && (N % 128) == 0 &&
        (K % 64) == 0 && K >= 128 && (nwg % 8) == 0) {
        char*  xq = (char*)d_ws;
        char*  qb = xq + xq_b;
        float* rs = (float*)(qb + qb_b);
        quantx_kernel<<<M, 256, 0, stream>>>(x, xq, rs, K);
        convq_kernel<<<2048, 256, 0, stream>>>(q, qb, (long)(qb_b / 16));
        qgemm_i8_kernel<<<nwg, 512, 49152, stream>>>(xq, qb, rs, scale, bias,
                                                     out, M, N, K);
    } else {
        dim3 grid(N / 128, M / 128);
        qgemm_fb_kernel<<<grid, 256, 0, stream>>>(x, q, scale, bias, out, M, N, K);
    }
}